// Round 1
// baseline (446.852 us; speedup 1.0000x reference)
//
#include <hip/hip_runtime.h>
#include <stdint.h>

#define Nn 16
#define Cc 128
#define Hh 128
#define Ww 128
#define HWc (Hh*Ww)          // 16384
#define NPIX (Nn*Hh*Ww)      // 262144
#define NHW 262144           // BN reduction count per channel

// ws layout (16B-aligned regions):
//   [0, 2048)                     : int64 stats  sum[128], sumsq[128]
//   [2048, 20480)                 : packed weight signs uint4[128*9]
//   [20480, 20480+4MB)            : packed x signs uint4[NPIX]
//   [+4MB, +8MB)                  : packed x nonzero uint4[NPIX]

__global__ __launch_bounds__(256) void pack_x_kernel(const float* __restrict__ x,
                                                     uint4* __restrict__ xs,
                                                     uint4* __restrict__ xz) {
    int pix = blockIdx.x * 256 + threadIdx.x;   // 0..NPIX-1
    int n   = pix >> 14;                        // / HWc
    int rem = pix & 16383;
    const float* px = x + (size_t)n * Cc * HWc + rem;
    uint32_t s[4] = {0,0,0,0}, z[4] = {0,0,0,0};
    #pragma unroll 4
    for (int cw = 0; cw < 4; ++cw) {
        #pragma unroll 32
        for (int b = 0; b < 32; ++b) {
            float v = px[(size_t)(cw*32 + b) * HWc];
            s[cw] |= (v < 0.0f  ? 1u : 0u) << b;
            z[cw] |= (v != 0.0f ? 1u : 0u) << b;
        }
    }
    xs[pix] = make_uint4(s[0], s[1], s[2], s[3]);
    xz[pix] = make_uint4(z[0], z[1], z[2], z[3]);
}

__global__ __launch_bounds__(256) void pack_w_kernel(const float* __restrict__ wt,
                                                     uint4* __restrict__ wp) {
    int t = blockIdx.x * 256 + threadIdx.x;
    if (t >= Cc * 9) return;
    int o = t / 9, tap = t % 9;
    const float* pw = wt + (size_t)o * (Cc * 9) + tap;
    uint32_t s[4] = {0,0,0,0};
    for (int c = 0; c < Cc; ++c) {
        float v = pw[(size_t)c * 9];
        s[c >> 5] |= (v < 0.0f ? 1u : 0u) << (c & 31);
    }
    wp[t] = make_uint4(s[0], s[1], s[2], s[3]);
}

__global__ __launch_bounds__(256) void conv_kernel(const uint4* __restrict__ xs,
                                                   const uint4* __restrict__ xz,
                                                   const uint4* __restrict__ wp,
                                                   float* __restrict__ out) {
    __shared__ uint4 wlds[Cc * 9];  // 18432 B
    for (int i = threadIdx.x; i < Cc * 9; i += 256) wlds[i] = wp[i];
    __syncthreads();

    int pix = blockIdx.x * 256 + threadIdx.x;
    int n   = pix >> 14;
    int rem = pix & 16383;
    int h = rem >> 7, w = rem & 127;

    uint4 s[9], z[9];
    int base = 0;
    #pragma unroll
    for (int dh = -1; dh <= 1; ++dh) {
        #pragma unroll
        for (int dw = -1; dw <= 1; ++dw) {
            int t = (dh + 1) * 3 + (dw + 1);
            int hh = h + dh, ww = w + dw;
            if (hh >= 0 && hh < Hh && ww >= 0 && ww < Ww) {
                int p = (n << 14) | (hh << 7) | ww;
                s[t] = xs[p];
                z[t] = xz[p];
                base += __popc(z[t].x) + __popc(z[t].y) + __popc(z[t].z) + __popc(z[t].w);
            } else {
                s[t] = make_uint4(0,0,0,0);
                z[t] = make_uint4(0,0,0,0);
            }
        }
    }

    float* po = out + (size_t)n * Cc * HWc + rem;
    for (int o = 0; o < Cc; ++o) {
        int acc = 0;
        #pragma unroll
        for (int t = 0; t < 9; ++t) {
            uint4 wv = wlds[o * 9 + t];
            acc += __popc((s[t].x ^ wv.x) & z[t].x);
            acc += __popc((s[t].y ^ wv.y) & z[t].y);
            acc += __popc((s[t].z ^ wv.z) & z[t].z);
            acc += __popc((s[t].w ^ wv.w) & z[t].w);
        }
        po[(size_t)o * HWc] = (float)(base - 2 * acc);
    }
}

__global__ __launch_bounds__(256) void stats_kernel(const float* __restrict__ conv,
                                                    unsigned long long* __restrict__ stats) {
    int b = blockIdx.x;            // 0..2047  -> (n, c)
    int c = b & 127, n = b >> 7;
    const float4* p = (const float4*)(conv + (size_t)(n * Cc + c) * HWc);
    int sum = 0, sq = 0;           // per-thread: |sum|<=73k, sq<=85M  (int32 safe)
    for (int i = threadIdx.x; i < HWc / 4; i += 256) {
        float4 v = p[i];
        int a = (int)v.x, d = (int)v.y, e = (int)v.z, f = (int)v.w;
        sum += a + d + e + f;
        sq  += a*a + d*d + e*e + f*f;
    }
    #pragma unroll
    for (int off = 32; off > 0; off >>= 1) {
        sum += __shfl_down(sum, off);
        sq  += __shfl_down(sq, off);
    }
    __shared__ int wsum[4], wsq[4];
    int wave = threadIdx.x >> 6, lane = threadIdx.x & 63;
    if (lane == 0) { wsum[wave] = sum; wsq[wave] = sq; }
    __syncthreads();
    if (threadIdx.x == 0) {
        int S = 0, Q = 0;   // block sq <= 256*1.33M = 340M < 2^31
        #pragma unroll
        for (int i = 0; i < 4; ++i) { S += wsum[i]; Q += wsq[i]; }
        atomicAdd(&stats[c],       (unsigned long long)(long long)S);
        atomicAdd(&stats[128 + c], (unsigned long long)(long long)Q);
    }
}

__global__ __launch_bounds__(256) void apply_kernel(float* __restrict__ out,
                                                    const float* __restrict__ x,
                                                    const unsigned long long* __restrict__ stats,
                                                    const float* __restrict__ gamma,
                                                    const float* __restrict__ beta) {
    int b = blockIdx.x;            // (n, c)
    int c = b & 127, n = b >> 7;
    size_t basei = (size_t)(n * Cc + c) * HWc;
    long long S = (long long)stats[c];
    long long Q = (long long)stats[128 + c];
    double m   = (double)S / (double)NHW;
    double var = (double)Q / (double)NHW - m * m;
    float inv   = (float)(1.0 / sqrt(var + 1e-5));
    float scale = inv * gamma[c];
    float shift = beta[c] - (float)m * scale;

    float4* po = (float4*)(out + basei);
    const float4* px = (const float4*)(x + basei);
    for (int i = threadIdx.x; i < HWc / 4; i += 256) {
        float4 v = po[i];
        float4 r = px[i];
        v.x = fminf(fmaxf(v.x * scale + shift, -1.0f), 1.0f) + r.x;
        v.y = fminf(fmaxf(v.y * scale + shift, -1.0f), 1.0f) + r.y;
        v.z = fminf(fmaxf(v.z * scale + shift, -1.0f), 1.0f) + r.z;
        v.w = fminf(fmaxf(v.w * scale + shift, -1.0f), 1.0f) + r.w;
        po[i] = v;
    }
}

extern "C" void kernel_launch(void* const* d_in, const int* in_sizes, int n_in,
                              void* d_out, int out_size, void* d_ws, size_t ws_size,
                              hipStream_t stream) {
    const float* x     = (const float*)d_in[0];
    const float* wt    = (const float*)d_in[1];
    const float* gamma = (const float*)d_in[2];
    const float* beta  = (const float*)d_in[3];
    float* out = (float*)d_out;

    char* ws = (char*)d_ws;
    unsigned long long* stats = (unsigned long long*)ws;          // 2048 B
    uint4* wp = (uint4*)(ws + 2048);                              // 18432 B
    uint4* xs = (uint4*)(ws + 20480);                             // 4 MB
    uint4* xz = (uint4*)(ws + 20480 + 4194304);                   // 4 MB

    hipMemsetAsync(stats, 0, 2048, stream);
    pack_x_kernel<<<NPIX / 256, 256, 0, stream>>>(x, xs, xz);
    pack_w_kernel<<<(Cc * 9 + 255) / 256, 256, 0, stream>>>(wt, wp);
    conv_kernel<<<NPIX / 256, 256, 0, stream>>>(xs, xz, wp, out);
    stats_kernel<<<Nn * Cc, 256, 0, stream>>>(out, stats);
    apply_kernel<<<Nn * Cc, 256, 0, stream>>>(out, x, stats, gamma, beta);
}

// Round 2
// 401.463 us; speedup vs baseline: 1.1131x; 1.1131x over previous
//
#include <hip/hip_runtime.h>
#include <stdint.h>

#define Nn 16
#define Cc 128
#define Hh 128
#define Ww 128
#define HWc (Hh*Ww)          // 16384
#define NPIX (Nn*Hh*Ww)      // 262144
#define NHW 262144

typedef int v4i  __attribute__((ext_vector_type(4)));
typedef int v16i __attribute__((ext_vector_type(16)));

// ws layout:
//   [0, 2048)        : stats  (u64-compatible sum[128] @0, sumsq[128] @1024)
//   [4096, 151552)   : wswz   swizzled int8 weight fragments (147456 B)
//   [262144, +32MB)  : x8     NHWC int8 sign(x)  (33554432 B)

// ---------------- pack x: NCHW fp32 -> NHWC int8 sign, via LDS transpose ----
__global__ __launch_bounds__(256) void pack_x(const float* __restrict__ x,
                                              char* __restrict__ x8) {
    __shared__ char tile[128 * 132];          // [w][c], stride 132 kills conflicts
    int bid = blockIdx.x;                     // n*128 + h
    int n = bid >> 7, h = bid & 127;
    const float* px = x + (((size_t)n * 128) * 128 + h) * 128;  // &x[n][0][h][0]
    int t = threadIdx.x;
    int w = t & 127, ch = t >> 7;
    for (int q = 0; q < 16; ++q) {
        int c = ch * 64 + q * 4;
        uint32_t d = 0;
        #pragma unroll
        for (int j = 0; j < 4; ++j) {
            float v = px[(size_t)(c + j) * HWc + w];
            int8_t s = (v > 0.f) ? 1 : ((v < 0.f) ? -1 : 0);
            d |= (uint32_t)(uint8_t)s << (8 * j);
        }
        *(uint32_t*)(tile + w * 132 + c) = d;
    }
    __syncthreads();
    char* dst = x8 + (size_t)bid * 16384;     // x8[n][h][w][c]
    for (int s = 0; s < 4; ++s) {
        int idx = s * 256 + t;
        int ww = idx >> 3, cb = idx & 7;
        const char* src = tile + ww * 132 + cb * 16;
        uint32_t a0 = *(const uint32_t*)(src + 0);
        uint32_t a1 = *(const uint32_t*)(src + 4);
        uint32_t a2 = *(const uint32_t*)(src + 8);
        uint32_t a3 = *(const uint32_t*)(src + 12);
        *(uint4*)(dst + ww * 128 + cb * 16) = make_uint4(a0, a1, a2, a3);
    }
}

// ---------------- pack w: OIHW fp32 -> A-fragment-linear int8 ----------------
// layout: [ot(4)][tap(9)][kh(4)][lane(64)][byte(16)]
// o = ot*32 + (lane&31),  c = kh*32 + (lane>>5)*16 + byte,  element w[o][c][tap]
__global__ __launch_bounds__(256) void pack_w(const float* __restrict__ wt,
                                              char* __restrict__ wswz) {
    int gid = blockIdx.x * 256 + threadIdx.x;   // 0..9215
    if (gid >= 9216) return;
    int lane = gid & 63, grp = gid >> 6;        // grp 0..143
    int kh = grp & 3, tap = (grp >> 2) % 9, ot = grp / 36;
    int o  = ot * 32 + (lane & 31);
    int cb = kh * 32 + (lane >> 5) * 16;
    uint32_t dw[4];
    #pragma unroll
    for (int di = 0; di < 4; ++di) {
        uint32_t d = 0;
        #pragma unroll
        for (int j = 0; j < 4; ++j) {
            int c = cb + di * 4 + j;
            float v = wt[((size_t)o * 128 + c) * 9 + tap];
            int8_t s = (v > 0.f) ? 1 : ((v < 0.f) ? -1 : 0);
            d |= (uint32_t)(uint8_t)s << (8 * j);
        }
        dw[di] = d;
    }
    *(uint4*)(wswz + (size_t)gid * 16) = make_uint4(dw[0], dw[1], dw[2], dw[3]);
}

// ---------------- conv: implicit GEMM, mfma_i32_32x32x32_i8 -----------------
// block = one (n,h) row: 128 pixels x 128 outputs. 4 waves, wave tile 64o x 64p.
__global__ __launch_bounds__(256) void conv_mfma(const char* __restrict__ x8,
                                                 const char* __restrict__ wswz,
                                                 float* __restrict__ out) {
    int bid = blockIdx.x;                     // n*128 + h
    int n = bid >> 7, h = bid & 127;
    int tid = threadIdx.x;
    int lane = tid & 63, wid = tid >> 6;
    int wy = wid >> 1, wx = wid & 1;
    int ln31 = lane & 31, lq = lane >> 5;

    v16i acc[2][2];
    #pragma unroll
    for (int oi = 0; oi < 2; ++oi)
        #pragma unroll
        for (int pi = 0; pi < 2; ++pi)
            #pragma unroll
            for (int r = 0; r < 16; ++r) acc[oi][pi][r] = 0;

    const char* xim = x8 + ((size_t)n * 128) * 16384;   // + h'*16384 + w'*128 + c
    int w2a = wx * 64 + ln31;        // pixel for pi=0 (before +dw)
    #pragma unroll
    for (int tap = 0; tap < 9; ++tap) {
        int dh = tap / 3 - 1, dw = tap % 3 - 1;
        int h2 = h + dh;
        bool rowok = (unsigned)h2 < 128u;
        int wa = w2a + dw, wb = wa + 32;
        bool va = rowok && ((unsigned)wa < 128u);
        bool vb = rowok && ((unsigned)wb < 128u);
        const char* prow  = xim + (size_t)h2 * 16384;
        const char* wbase = wswz + (size_t)((wy * 2) * 9 + tap) * 4096;
        #pragma unroll
        for (int kh = 0; kh < 4; ++kh) {
            int co = kh * 32 + lq * 16;
            v4i a0 = *(const v4i*)(wbase + kh * 1024 + lane * 16);
            v4i a1 = *(const v4i*)(wbase + 9 * 4096 + kh * 1024 + lane * 16);
            v4i b0; v4i b1;
            #pragma unroll
            for (int r = 0; r < 4; ++r) { b0[r] = 0; b1[r] = 0; }
            if (va) b0 = *(const v4i*)(prow + (size_t)wa * 128 + co);
            if (vb) b1 = *(const v4i*)(prow + (size_t)wb * 128 + co);
            acc[0][0] = __builtin_amdgcn_mfma_i32_32x32x32_i8(a0, b0, acc[0][0], 0, 0, 0);
            acc[0][1] = __builtin_amdgcn_mfma_i32_32x32x32_i8(a0, b1, acc[0][1], 0, 0, 0);
            acc[1][0] = __builtin_amdgcn_mfma_i32_32x32x32_i8(a1, b0, acc[1][0], 0, 0, 0);
            acc[1][1] = __builtin_amdgcn_mfma_i32_32x32x32_i8(a1, b1, acc[1][1], 0, 0, 0);
        }
    }

    // epilogue: D[row=o][col=pixel]; row=(reg&3)+8*(reg>>2)+4*(lane>>5), col=lane&31
    float* po = out + ((size_t)n * 128) * HWc + (size_t)h * 128;
    #pragma unroll
    for (int oi = 0; oi < 2; ++oi)
        #pragma unroll
        for (int pi = 0; pi < 2; ++pi) {
            int wcol = wx * 64 + pi * 32 + ln31;
            #pragma unroll
            for (int r = 0; r < 16; ++r) {
                int orow = wy * 64 + oi * 32 + (r & 3) + 8 * (r >> 2) + 4 * lq;
                po[(size_t)orow * HWc + wcol] = (float)acc[oi][pi][r];
            }
        }
}

// ---------------- stats: per-channel integer sum / sumsq --------------------
__global__ __launch_bounds__(256) void stats_kernel(const float* __restrict__ conv,
                                                    unsigned long long* __restrict__ stats) {
    int b = blockIdx.x;            // (n, c)
    int c = b & 127, n = b >> 7;
    const float4* p = (const float4*)(conv + (size_t)(n * Cc + c) * HWc);
    int sum = 0, sq = 0;
    for (int i = threadIdx.x; i < HWc / 4; i += 256) {
        float4 v = p[i];
        int a = (int)v.x, d = (int)v.y, e = (int)v.z, f = (int)v.w;
        sum += a + d + e + f;
        sq  += a * a + d * d + e * e + f * f;
    }
    #pragma unroll
    for (int off = 32; off > 0; off >>= 1) {
        sum += __shfl_down(sum, off);
        sq  += __shfl_down(sq, off);
    }
    __shared__ int wsum[4], wsq[4];
    int wave = threadIdx.x >> 6, lane = threadIdx.x & 63;
    if (lane == 0) { wsum[wave] = sum; wsq[wave] = sq; }
    __syncthreads();
    if (threadIdx.x == 0) {
        int S = 0, Q = 0;
        #pragma unroll
        for (int i = 0; i < 4; ++i) { S += wsum[i]; Q += wsq[i]; }
        atomicAdd(&stats[c],       (unsigned long long)(long long)S);
        atomicAdd(&stats[128 + c], (unsigned long long)(long long)Q);
    }
}

// ---------------- apply: BN + hardtanh + residual, in place -----------------
__global__ __launch_bounds__(256) void apply_kernel(float* __restrict__ out,
                                                    const float* __restrict__ x,
                                                    const unsigned long long* __restrict__ stats,
                                                    const float* __restrict__ gamma,
                                                    const float* __restrict__ beta) {
    int b = blockIdx.x;            // (n, c)
    int c = b & 127, n = b >> 7;
    size_t basei = (size_t)(n * Cc + c) * HWc;
    long long S = (long long)stats[c];
    long long Q = (long long)stats[128 + c];
    double m   = (double)S / (double)NHW;
    double var = (double)Q / (double)NHW - m * m;
    float inv   = (float)(1.0 / sqrt(var + 1e-5));
    float scale = inv * gamma[c];
    float shift = beta[c] - (float)m * scale;

    float4* po = (float4*)(out + basei);
    const float4* px = (const float4*)(x + basei);
    for (int i = threadIdx.x; i < HWc / 4; i += 256) {
        float4 v = po[i];
        float4 r = px[i];
        v.x = fminf(fmaxf(v.x * scale + shift, -1.0f), 1.0f) + r.x;
        v.y = fminf(fmaxf(v.y * scale + shift, -1.0f), 1.0f) + r.y;
        v.z = fminf(fmaxf(v.z * scale + shift, -1.0f), 1.0f) + r.z;
        v.w = fminf(fmaxf(v.w * scale + shift, -1.0f), 1.0f) + r.w;
        po[i] = v;
    }
}

extern "C" void kernel_launch(void* const* d_in, const int* in_sizes, int n_in,
                              void* d_out, int out_size, void* d_ws, size_t ws_size,
                              hipStream_t stream) {
    const float* x     = (const float*)d_in[0];
    const float* wt    = (const float*)d_in[1];
    const float* gamma = (const float*)d_in[2];
    const float* beta  = (const float*)d_in[3];
    float* out = (float*)d_out;

    char* ws = (char*)d_ws;
    unsigned long long* stats = (unsigned long long*)ws;    // 2048 B
    char* wswz = ws + 4096;                                 // 147456 B
    char* x8   = ws + 262144;                               // 33554432 B

    hipMemsetAsync(stats, 0, 2048, stream);
    pack_x<<<Nn * Hh, 256, 0, stream>>>(x, x8);
    pack_w<<<36, 256, 0, stream>>>(wt, wswz);
    conv_mfma<<<Nn * Hh, 256, 0, stream>>>(x8, wswz, out);
    stats_kernel<<<Nn * Cc, 256, 0, stream>>>(out, stats);
    apply_kernel<<<Nn * Cc, 256, 0, stream>>>(out, x, stats, gamma, beta);
}

// Round 3
// 362.945 us; speedup vs baseline: 1.2312x; 1.1061x over previous
//
#include <hip/hip_runtime.h>
#include <stdint.h>

#define Nn 16
#define Cc 128
#define Hh 128
#define Ww 128
#define HWc (Hh*Ww)          // 16384
#define NHW 262144

#define PIXB 132             // bytes per pixel slot (128 data + 4 pad) -> 33 dwords
#define ROWP 17408           // global/LDS row pitch bytes (17*1024, >= 130*132=17160)
#define NROW 130             // rows per image incl. top/bottom halo

typedef int v4i  __attribute__((ext_vector_type(4)));
typedef int v16i __attribute__((ext_vector_type(16)));

typedef __attribute__((address_space(3))) unsigned int lds_uint;
typedef __attribute__((address_space(1))) const unsigned int glob_uint;

__device__ __forceinline__ void gload_lds16(const void* g, void* l) {
    __builtin_amdgcn_global_load_lds((glob_uint*)g, (lds_uint*)l, 16, 0, 0);
}

// ---------------- pack x: NCHW fp32 -> padded [n][130][row] int8 sign -------
// row r holds h = r-1; pixel slot p (0..129) holds w = p-1; slot = 132 B (128 c + 4 pad)
__global__ __launch_bounds__(256) void pack_x(const float* __restrict__ x,
                                              char* __restrict__ x8) {
    int bid = blockIdx.x;                 // n*130 + r
    int n = bid / NROW, r = bid % NROW;
    char* row = x8 + (size_t)bid * ROWP;
    int t = threadIdx.x;

    if (r == 0 || r == NROW - 1) {        // halo row: zero all
        for (int i = t; i < ROWP / 16; i += 256)
            ((uint4*)row)[i] = make_uint4(0, 0, 0, 0);
        return;
    }
    int h = r - 1;
    // zero left/right halo pixel slots (33 dwords each)
    if (t < 33)                ((uint32_t*)row)[t] = 0;
    else if (t >= 64 && t < 97) ((uint32_t*)(row + 129 * PIXB))[t - 64] = 0;

    __shared__ char tile[128 * PIXB];     // [w][c] transpose tile
    const float* px = x + (((size_t)n * Cc) * Hh + h) * Ww;   // &x[n][0][h][0]
    int w = t & 127, ch = t >> 7;
    for (int q = 0; q < 16; ++q) {
        int c = ch * 64 + q * 4;
        uint32_t d = 0;
        #pragma unroll
        for (int j = 0; j < 4; ++j) {
            float v = px[(size_t)(c + j) * HWc + w];
            int8_t s = (v > 0.f) ? 1 : ((v < 0.f) ? -1 : 0);
            d |= (uint32_t)(uint8_t)s << (8 * j);
        }
        *(uint32_t*)(tile + w * PIXB + c) = d;
    }
    __syncthreads();
    for (int s = 0; s < 4; ++s) {
        int idx = s * 256 + t;            // 1024 chunks of 16 B
        int ww = idx >> 3, cb = idx & 7;
        const uint32_t* src = (const uint32_t*)(tile + ww * PIXB + cb * 16);
        uint32_t* dst = (uint32_t*)(row + (1 + ww) * PIXB + cb * 16);
        dst[0] = src[0]; dst[1] = src[1]; dst[2] = src[2]; dst[3] = src[3];
    }
}

// ---------------- pack w: OIHW fp32 -> A-fragment-linear int8 ----------------
__global__ __launch_bounds__(256) void pack_w(const float* __restrict__ wt,
                                              char* __restrict__ wswz) {
    int gid = blockIdx.x * 256 + threadIdx.x;   // 0..9215
    if (gid >= 9216) return;
    int lane = gid & 63, grp = gid >> 6;        // grp 0..143
    int kh = grp & 3, tap = (grp >> 2) % 9, ot = grp / 36;
    int o  = ot * 32 + (lane & 31);
    int cb = kh * 32 + (lane >> 5) * 16;
    uint32_t dw4[4];
    #pragma unroll
    for (int di = 0; di < 4; ++di) {
        uint32_t d = 0;
        #pragma unroll
        for (int j = 0; j < 4; ++j) {
            int c = cb + di * 4 + j;
            float v = wt[((size_t)o * Cc + c) * 9 + tap];
            int8_t s = (v > 0.f) ? 1 : ((v < 0.f) ? -1 : 0);
            d |= (uint32_t)(uint8_t)s << (8 * j);
        }
        dw4[di] = d;
    }
    *(uint4*)(wswz + (size_t)gid * 16) = make_uint4(dw4[0], dw4[1], dw4[2], dw4[3]);
}

// ---------------- conv: LDS-staged implicit GEMM, mfma_i32_32x32x32_i8 ------
template <typename OutT>
__global__ __launch_bounds__(256) void conv_mfma2(const char* __restrict__ x8,
                                                  const char* __restrict__ wswz,
                                                  OutT* __restrict__ out) {
    __shared__ char lds[3 * ROWP];        // 52224 B
    int bid = blockIdx.x;                 // n*128 + h
    int n = bid >> 7, h = bid & 127;
    int tid = threadIdx.x, lane = tid & 63, wid = tid >> 6;

    // stage global rows h, h+1, h+2 (= image rows h-1, h, h+1, halo-zeroed)
    const char* gbase = x8 + ((size_t)n * NROW + h) * ROWP;
    for (int task = wid; task < 51; task += 4) {   // 3 rows x 17 KB-chunks
        int rr = task / 17, ck = task % 17;
        gload_lds16(gbase + (size_t)rr * ROWP + ck * 1024 + lane * 16,
                    lds + rr * ROWP + ck * 1024);
    }
    __syncthreads();

    int wy = wid >> 1, wx = wid & 1;
    int ln31 = lane & 31, lq = lane >> 5;

    v16i acc[2][2];
    #pragma unroll
    for (int oi = 0; oi < 2; ++oi)
        #pragma unroll
        for (int pi = 0; pi < 2; ++pi)
            #pragma unroll
            for (int r2 = 0; r2 < 16; ++r2) acc[oi][pi][r2] = 0;

    const char* wb0 = wswz + (size_t)(wy * 2 * 9) * 4096 + lane * 16;
    const char* lb  = lds + (1 + wx * 64 + ln31) * PIXB + lq * 16;   // pi=0 pixel base

    #pragma unroll
    for (int tap = 0; tap < 9; ++tap) {
        int rr = tap / 3, dw = tap % 3 - 1;
        #pragma unroll
        for (int kh = 0; kh < 4; ++kh) {
            v4i a0 = *(const v4i*)(wb0 + (tap * 4 + kh) * 1024);
            v4i a1 = *(const v4i*)(wb0 + (36 + tap * 4 + kh) * 1024);
            const uint32_t* p0 = (const uint32_t*)(lb + rr * ROWP + dw * PIXB + kh * 32);
            const uint32_t* p1 = p0 + (32 * PIXB) / 4;
            v4i b0, b1;
            #pragma unroll
            for (int j = 0; j < 4; ++j) { b0[j] = (int)p0[j]; b1[j] = (int)p1[j]; }
            acc[0][0] = __builtin_amdgcn_mfma_i32_32x32x32_i8(a0, b0, acc[0][0], 0, 0, 0);
            acc[0][1] = __builtin_amdgcn_mfma_i32_32x32x32_i8(a0, b1, acc[0][1], 0, 0, 0);
            acc[1][0] = __builtin_amdgcn_mfma_i32_32x32x32_i8(a1, b0, acc[1][0], 0, 0, 0);
            acc[1][1] = __builtin_amdgcn_mfma_i32_32x32x32_i8(a1, b1, acc[1][1], 0, 0, 0);
        }
    }

    // epilogue: D[row=o][col=pixel]; row=(r&3)+8*(r>>2)+4*lq, col=ln31
    OutT* po = out + ((size_t)n * Cc) * HWc + (size_t)h * Ww;
    #pragma unroll
    for (int oi = 0; oi < 2; ++oi)
        #pragma unroll
        for (int pi = 0; pi < 2; ++pi) {
            int wcol = wx * 64 + pi * 32 + ln31;
            #pragma unroll
            for (int r2 = 0; r2 < 16; ++r2) {
                int orow = wy * 64 + oi * 32 + (r2 & 3) + 8 * (r2 >> 2) + 4 * lq;
                po[(size_t)orow * HWc + wcol] = (OutT)acc[oi][pi][r2];
            }
        }
}

// ---------------- stats (int16 conv) ----------------------------------------
__global__ __launch_bounds__(256) void stats16(const short* __restrict__ conv,
                                               unsigned long long* __restrict__ stats) {
    int b = blockIdx.x;            // (n, c)
    int c = b & 127, n = b >> 7;
    const uint4* p = (const uint4*)(conv + (size_t)(n * Cc + c) * HWc);
    int sum = 0, sq = 0;
    for (int i = threadIdx.x; i < HWc / 8; i += 256) {
        uint4 v = p[i];
        uint32_t ua[4] = {v.x, v.y, v.z, v.w};
        #pragma unroll
        for (int j = 0; j < 4; ++j) {
            int s0 = (short)(ua[j] & 0xffff), s1 = (short)(ua[j] >> 16);
            sum += s0 + s1;
            sq  += s0 * s0 + s1 * s1;
        }
    }
    #pragma unroll
    for (int off = 32; off > 0; off >>= 1) {
        sum += __shfl_down(sum, off);
        sq  += __shfl_down(sq, off);
    }
    __shared__ int wsum[4], wsq[4];
    int wave = threadIdx.x >> 6, lane = threadIdx.x & 63;
    if (lane == 0) { wsum[wave] = sum; wsq[wave] = sq; }
    __syncthreads();
    if (threadIdx.x == 0) {
        long long S = 0, Q = 0;
        #pragma unroll
        for (int i = 0; i < 4; ++i) { S += wsum[i]; Q += wsq[i]; }
        atomicAdd(&stats[c],       (unsigned long long)S);
        atomicAdd(&stats[128 + c], (unsigned long long)Q);
    }
}

__global__ __launch_bounds__(256) void statsf(const float* __restrict__ conv,
                                              unsigned long long* __restrict__ stats) {
    int b = blockIdx.x;
    int c = b & 127, n = b >> 7;
    const float4* p = (const float4*)(conv + (size_t)(n * Cc + c) * HWc);
    int sum = 0, sq = 0;
    for (int i = threadIdx.x; i < HWc / 4; i += 256) {
        float4 v = p[i];
        int a = (int)v.x, d = (int)v.y, e = (int)v.z, f = (int)v.w;
        sum += a + d + e + f;
        sq  += a * a + d * d + e * e + f * f;
    }
    #pragma unroll
    for (int off = 32; off > 0; off >>= 1) {
        sum += __shfl_down(sum, off);
        sq  += __shfl_down(sq, off);
    }
    __shared__ int wsum[4], wsq[4];
    int wave = threadIdx.x >> 6, lane = threadIdx.x & 63;
    if (lane == 0) { wsum[wave] = sum; wsq[wave] = sq; }
    __syncthreads();
    if (threadIdx.x == 0) {
        long long S = 0, Q = 0;
        #pragma unroll
        for (int i = 0; i < 4; ++i) { S += wsum[i]; Q += wsq[i]; }
        atomicAdd(&stats[c],       (unsigned long long)S);
        atomicAdd(&stats[128 + c], (unsigned long long)Q);
    }
}

// ---------------- apply: BN + hardtanh + residual ----------------------------
__device__ __forceinline__ void bn_coef(const unsigned long long* stats,
                                        const float* gamma, const float* beta,
                                        int c, float& scale, float& shift) {
    long long S = (long long)stats[c];
    long long Q = (long long)stats[128 + c];
    double m   = (double)S / (double)NHW;
    double var = (double)Q / (double)NHW - m * m;
    float inv  = (float)(1.0 / sqrt(var + 1e-5));
    scale = inv * gamma[c];
    shift = beta[c] - (float)m * scale;
}

__global__ __launch_bounds__(256) void apply16(float* __restrict__ out,
                                               const short* __restrict__ conv,
                                               const float* __restrict__ x,
                                               const unsigned long long* __restrict__ stats,
                                               const float* __restrict__ gamma,
                                               const float* __restrict__ beta) {
    int b = blockIdx.x;            // (n, c)
    int c = b & 127, n = b >> 7;
    size_t basei = (size_t)(n * Cc + c) * HWc;
    float scale, shift;
    bn_coef(stats, gamma, beta, c, scale, shift);

    const uint4*  pc = (const uint4*)(conv + basei);   // 8 vals / 16 B
    const float4* px = (const float4*)(x + basei);
    float4*       po = (float4*)(out + basei);
    for (int i = threadIdx.x; i < HWc / 8; i += 256) {
        uint4 v = pc[i];
        uint32_t ua[4] = {v.x, v.y, v.z, v.w};
        #pragma unroll
        for (int half = 0; half < 2; ++half) {
            float4 r = px[i * 2 + half];
            float4 o;
            float c0 = (float)(short)(ua[half * 2]     & 0xffff);
            float c1 = (float)(short)(ua[half * 2]     >> 16);
            float c2 = (float)(short)(ua[half * 2 + 1] & 0xffff);
            float c3 = (float)(short)(ua[half * 2 + 1] >> 16);
            o.x = fminf(fmaxf(c0 * scale + shift, -1.0f), 1.0f) + r.x;
            o.y = fminf(fmaxf(c1 * scale + shift, -1.0f), 1.0f) + r.y;
            o.z = fminf(fmaxf(c2 * scale + shift, -1.0f), 1.0f) + r.z;
            o.w = fminf(fmaxf(c3 * scale + shift, -1.0f), 1.0f) + r.w;
            po[i * 2 + half] = o;
        }
    }
}

__global__ __launch_bounds__(256) void applyf(float* __restrict__ out,
                                              const float* __restrict__ x,
                                              const unsigned long long* __restrict__ stats,
                                              const float* __restrict__ gamma,
                                              const float* __restrict__ beta) {
    int b = blockIdx.x;
    int c = b & 127, n = b >> 7;
    size_t basei = (size_t)(n * Cc + c) * HWc;
    float scale, shift;
    bn_coef(stats, gamma, beta, c, scale, shift);

    float4* po = (float4*)(out + basei);
    const float4* px = (const float4*)(x + basei);
    for (int i = threadIdx.x; i < HWc / 4; i += 256) {
        float4 v = po[i];
        float4 r = px[i];
        v.x = fminf(fmaxf(v.x * scale + shift, -1.0f), 1.0f) + r.x;
        v.y = fminf(fmaxf(v.y * scale + shift, -1.0f), 1.0f) + r.y;
        v.z = fminf(fmaxf(v.z * scale + shift, -1.0f), 1.0f) + r.z;
        v.w = fminf(fmaxf(v.w * scale + shift, -1.0f), 1.0f) + r.w;
        po[i] = v;
    }
}

extern "C" void kernel_launch(void* const* d_in, const int* in_sizes, int n_in,
                              void* d_out, int out_size, void* d_ws, size_t ws_size,
                              hipStream_t stream) {
    const float* x     = (const float*)d_in[0];
    const float* wt    = (const float*)d_in[1];
    const float* gamma = (const float*)d_in[2];
    const float* beta  = (const float*)d_in[3];
    float* out = (float*)d_out;

    char* ws = (char*)d_ws;
    unsigned long long* stats = (unsigned long long*)ws;      // 2048 B
    char* wswz = ws + 4096;                                   // 147456 B
    char* x8   = ws + 262144;                                 // 16*130*17408 = 36208640 B
    const size_t x8_bytes = (size_t)Nn * NROW * ROWP;
    short* conv16 = (short*)(ws + 262144 + x8_bytes);         // 67108864 B
    const size_t need16 = 262144 + x8_bytes + (size_t)NHW * Cc * 2;

    hipMemsetAsync(stats, 0, 2048, stream);
    pack_x<<<Nn * NROW, 256, 0, stream>>>(x, x8);
    pack_w<<<36, 256, 0, stream>>>(wt, wswz);

    if (ws_size >= need16) {
        conv_mfma2<short><<<Nn * Hh, 256, 0, stream>>>(x8, wswz, conv16);
        stats16<<<Nn * Cc, 256, 0, stream>>>(conv16, stats);
        apply16<<<Nn * Cc, 256, 0, stream>>>(out, conv16, x, stats, gamma, beta);
    } else {
        conv_mfma2<float><<<Nn * Hh, 256, 0, stream>>>(x8, wswz, out);
        statsf<<<Nn * Cc, 256, 0, stream>>>(out, stats);
        applyf<<<Nn * Cc, 256, 0, stream>>>(out, x, stats, gamma, beta);
    }
}